// Round 9
// baseline (132.124 us; speedup 1.0000x reference)
//
#include <hip/hip_runtime.h>
#include <hip/hip_bf16.h>

// Problem constants
#define BATCH 32
#define LTOT 4096
#define CCH 64
#define NFFT 16
#define HOP 4
#define NF 9            // n_fft/2+1
#define T_FR 1025       // 1 + L/HOP
#define ICH 576         // C * NF
#define OCH 512
#define TY 1023         // conv output length
#define OUTW 128
#define KTOT 1728       // 3 taps x 576

typedef __attribute__((ext_vector_type(8))) _Float16 half8;
typedef __attribute__((ext_vector_type(4))) float floatx4;

// cos/sin(n*pi/8) for n = 0..15 — compile-time twiddles.
__device__ constexpr float C16[16] = {
    1.0f,  0.923879533f,  0.707106781f,  0.382683432f,  0.0f, -0.382683432f,
   -0.707106781f, -0.923879533f, -1.0f, -0.923879533f, -0.707106781f,
   -0.382683432f,  0.0f,  0.382683432f,  0.707106781f,  0.923879533f};
__device__ constexpr float S16[16] = {
    0.0f,  0.382683432f,  0.707106781f,  0.923879533f,  1.0f,  0.923879533f,
    0.707106781f,  0.382683432f,  0.0f, -0.382683432f, -0.707106781f,
   -0.923879533f, -1.0f, -0.923879533f, -0.707106781f, -0.382683432f};

__device__ __forceinline__ void async_copy16(const _Float16* g, _Float16* l) {
  __builtin_amdgcn_global_load_lds(
      (const __attribute__((address_space(1))) unsigned int*)g,
      (__attribute__((address_space(3))) unsigned int*)l, 16, 0, 0);
}

// ---------------------------------------------------------------------------
// Kernel 1 (R23): STFT magnitude + bin-pool FUSED (+ weight repack).
// R22 split: stft wrote m_ws (36 MB), pmean re-read it (36 MB) and reduced
// 8x -> ~70 MB of HBM traffic existed only to link the two memory-floor
// kernels.  Fused: one block per (w-bin, b) computes rows s..e+1 of m
// (covers taps 0..2; t+k <= 1024 < T_FR so no zero rows) from x directly,
// rounds each magnitude through fp16 (numerics == R22 path), accumulates
// per-tap bin sums in registers, reduces across the 4 t-phases via LDS
// (wave==tq -> conflict-free), writes pm[b][w][1728] fp16.  m_ws deleted.
// Redundant row recompute at bin overlaps: 1.37x on a ~9 us VALU bill.
// block 256 = 64 c x 4 tq; grid (128 w, 32 b).
// LDS: xs (x window, <=56 rows fp32) and red (4x27x64 fp32) UNIONED via
// barrier (27.6 KB) -> 5 blocks/CU.
// ---------------------------------------------------------------------------
__global__ __launch_bounds__(256) void stft_pool_kernel(
    const float* __restrict__ x, const float* __restrict__ weight,
    _Float16* __restrict__ pm, _Float16* __restrict__ wkr) {
  const int w = blockIdx.x, b = blockIdx.y;
  const int tid = threadIdx.x;

  // ---- weight repack slice (independent; first 1152 blocks cover it) ----
  const int gid = (b * 128 + w) * 256 + tid;
  if (gid < OCH * ICH) {
    int o = gid / ICH, i = gid - o * ICH;
    int c = i / 9, f = i - c * 9;
    const float* src = weight + (size_t)o * (ICH * 3) + i * 3;
    _Float16* dst = wkr + (size_t)o * KTOT + f * 64 + c;
#pragma unroll
    for (int k = 0; k < 3; ++k)
      dst[k * ICH] = (_Float16)src[k];
  }

  // ---- bin geometry ----
  const int s = (w * TY) >> 7;                 // first conv-output row of bin
  const int e = ((w + 1) * TY + 127) >> 7;     // one past last
  const int cnt = e - s;                       // 8 or 9
  const int R = cnt + 2;                       // m rows s..e+1 (taps 0..2)
  const float inv = 1.0f / (float)cnt;

  __shared__ float arena[4 * 27 * 64];         // 27.6 KB union: xs | red
  float* xs = arena;                           // [R*4+12 <= 56][64]
  float* red = arena;                          // [4][27][64] after barrier

  // ---- stage x rows l_base .. l_base+nrow-1 (reflect-padded), float4 ----
  const int l_base = s * 4 - 8;
  const int nrow = R * 4 + 12;                 // <= 56
  const float* xb = x + (size_t)b * LTOT * CCH;
#pragma unroll
  for (int it = 0; it < 4; ++it) {
    int u = it * 256 + tid;
    int r = u >> 4, c4 = u & 15;
    if (r < nrow) {
      int l = l_base + r;
      if (l < 0) l = -l;
      if (l >= LTOT) l = 2 * LTOT - 2 - l;
      *(floatx4*)(&xs[r * 64 + c4 * 4]) =
          *(const floatx4*)(&xb[(size_t)l * CCH + c4 * 4]);
    }
  }
  __syncthreads();

  const int c = tid & 63, tq = tid >> 6;       // wave == tq

  float acc[3][NF];
#pragma unroll
  for (int k = 0; k < 3; ++k)
#pragma unroll
    for (int f = 0; f < NF; ++f) acc[k][f] = 0.0f;

  // ---- rows tq, tq+4, tq+8 ----
#pragma unroll
  for (int it = 0; it < 3; ++it) {
    const int rl = tq + it * 4;                // local m-row index
    if (rl < R) {
      float wx[16];
#pragma unroll
      for (int j = 0; j < 16; ++j)
        wx[j] = xs[(rl * 4 + j) * 64 + c] * (0.5f * (1.0f - C16[j]));
      float sj[8], dj[8];
#pragma unroll
      for (int j = 1; j < 8; ++j) {
        sj[j] = wx[j] + wx[16 - j];
        dj[j] = wx[j] - wx[16 - j];
      }
#pragma unroll
      for (int f = 0; f < NF; ++f) {
        float re = wx[0] + ((f & 1) ? -wx[8] : wx[8]);
        float im = 0.0f;
#pragma unroll
        for (int j = 1; j < 8; ++j) {
          re += sj[j] * C16[(f * j) & 15];
          im += dj[j] * S16[(f * j) & 15];
        }
        // round through fp16 first (matches the m_ws-materialized numerics)
        const float mag = (float)(_Float16)sqrtf(re * re + im * im);
        // row rl contributes to tap k iff rl-k in [0, cnt)
#pragma unroll
        for (int k = 0; k < 3; ++k)
          if ((unsigned)(rl - k) < (unsigned)cnt) acc[k][f] += mag;
      }
    }
  }

  __syncthreads();   // xs dead; arena becomes red

  // ---- write per-phase partials: red[tq][k*9+f][c] ----
#pragma unroll
  for (int k = 0; k < 3; ++k)
#pragma unroll
    for (int f = 0; f < NF; ++f)
      red[((tq * 27) + k * 9 + f) * 64 + c] = acc[k][f];
  __syncthreads();

  // ---- reduce 4 phases, mean, fp16, store pm[b][w][kappa] ----
  _Float16* pmo = pm + ((size_t)b * OUTW + w) * KTOT;
  for (int j = tid; j < KTOT; j += 256) {
    const int k = j / ICH;
    const int rem = j - k * ICH;
    const int f = rem >> 6;                    // kappa = k*576 + f*64 + c
    const int cc = rem & 63;
    const int base = (k * 9 + f) * 64 + cc;
    const float sum = red[base] + red[27 * 64 + base] +
                      red[2 * 27 * 64 + base] + red[3 * 27 * 64 + base];
    pmo[j] = (_Float16)(sum * inv);
  }
}

// ---------------------------------------------------------------------------
// Kernel 2 (R22, unchanged): the collapsed GEMM.
//   out[b][w][o] = bias[o] + sum_{kappa<1728} wkr[o][kappa]*pmean[b][w][kappa]
// Tile 64(o) x 128(w = one batch), grid 256 = 1 block/CU; proven R13
// fragment/staging swizzle (conflict-free 16-row fragments).
// XCD map: all 8 o-tiles of batch b on one XCD; b = bq*8 + xcd.
// ---------------------------------------------------------------------------
__global__ __launch_bounds__(256, 2) void gemm_pooled_kernel(
    const _Float16* __restrict__ pm, const _Float16* __restrict__ wkr,
    const float* __restrict__ bias, float* __restrict__ out) {
  const int lid = blockIdx.x;            // 0..255
  const int xcd = lid & 7;
  const int rest = lid >> 3;             // 0..31
  const int m8 = rest & 7;               // o-tile 0..7
  const int bq = rest >> 3;              // 0..3
  const int b = bq * 8 + xcd;
  const int o0 = m8 * 64;

  const int tid = threadIdx.x;
  const int wave = tid >> 6, lane = tid & 63;
  const int wm = wave >> 1, wn = wave & 1;   // 2(o) x 2(w) wave grid

  __shared__ _Float16 as[64 * 64];       // 8 KB  (W rows o0..o0+63)
  __shared__ _Float16 bs[128 * 64];      // 16 KB (pmean rows, all w of b)

  floatx4 acc[2][4];
#pragma unroll
  for (int mt = 0; mt < 2; ++mt)
#pragma unroll
    for (int nt = 0; nt < 4; ++nt)
      acc[mt][nt] = (floatx4)0.0f;

  const int frow = lane & 15;
  const int quad = lane >> 4;
  const int l7 = lane & 7;
  const int srow = lane >> 3;
  const int ssrc_off = srow * KTOT + (l7 ^ srow) * 8;

  const _Float16* ab = wkr + (size_t)o0 * KTOT;
  const _Float16* bb = pm + (size_t)b * OUTW * KTOT;

  for (int kb = 0; kb < 27; ++kb) {
    const int i0 = kb * 64;
    // stage A: 8 segs of 8 rows (2 per wave)
#pragma unroll
    for (int it = 0; it < 2; ++it) {
      const int seg = wave * 2 + it;
      async_copy16(ab + (size_t)(seg * 8) * KTOT + i0 + ssrc_off,
                   &as[seg * 512]);
    }
    // stage B: 16 segs of 8 rows (4 per wave)
#pragma unroll
    for (int it = 0; it < 4; ++it) {
      const int seg = wave * 4 + it;
      async_copy16(bb + (size_t)(seg * 8) * KTOT + i0 + ssrc_off,
                   &bs[seg * 512]);
    }
    __syncthreads();   // drains vmcnt + barrier

#pragma unroll
    for (int kk2 = 0; kk2 < 2; ++kk2) {
      const int jj = kk2 * 4 + quad;
      const int coff = ((jj ^ l7) << 3);
      half8 af[2], bf[4];
#pragma unroll
      for (int mt = 0; mt < 2; ++mt)
        af[mt] = *(const half8*)(&as[(wm * 32 + mt * 16 + frow) * 64 + coff]);
#pragma unroll
      for (int nt = 0; nt < 4; ++nt)
        bf[nt] = *(const half8*)(&bs[(wn * 64 + nt * 16 + frow) * 64 + coff]);
      // first operand = w-fragment => D row (quad*4+reg) = w, D col = o
#pragma unroll
      for (int mt = 0; mt < 2; ++mt)
#pragma unroll
        for (int nt = 0; nt < 4; ++nt)
          acc[mt][nt] = __builtin_amdgcn_mfma_f32_16x16x32_f16(
              bf[nt], af[mt], acc[mt][nt], 0, 0, 0);
    }
    __syncthreads();
  }

  // epilogue: out[b][w][o] fp32 = bias + acc.  mt inner => 128 B contiguous
  // per (nt,r) per wave (L2 write-combine pattern).
  const int col = lane & 15;
  float* ob = out + (size_t)b * OUTW * OCH;
#pragma unroll
  for (int nt = 0; nt < 4; ++nt) {
    const int wb = wn * 64 + nt * 16 + quad * 4;
#pragma unroll
    for (int r = 0; r < 4; ++r) {
      const int w = wb + r;
#pragma unroll
      for (int mt = 0; mt < 2; ++mt) {
        const int o = o0 + wm * 32 + mt * 16 + col;
        ob[(size_t)w * OCH + o] = bias[o] + acc[mt][nt][r];
      }
    }
  }
}

// ---------------------------------------------------------------------------
extern "C" void kernel_launch(void* const* d_in, const int* in_sizes, int n_in,
                              void* d_out, int out_size, void* d_ws, size_t ws_size,
                              hipStream_t stream) {
  const float* x = (const float*)d_in[0];       // [32, 4096, 64]
  const float* weight = (const float*)d_in[1];  // [512, 576, 3]
  const float* bias = (const float*)d_in[2];    // [512]
  float* out = (float*)d_out;                   // [32, 128, 512]

  char* ws = (char*)d_ws;
  const size_t w_bytes = (size_t)OCH * KTOT * sizeof(_Float16);  // 1,769,472
  _Float16* wkr = (_Float16*)ws;
  _Float16* pm = (_Float16*)(ws + w_bytes);   // [32][128][1728] fp16, 14.2 MB

  hipLaunchKernelGGL(stft_pool_kernel, dim3(OUTW, BATCH), dim3(256), 0,
                     stream, x, weight, pm, wkr);
  hipLaunchKernelGGL(gemm_pooled_kernel, dim3(256), dim3(256), 0, stream,
                     pm, wkr, bias, out);
}

// Round 10
// 124.876 us; speedup vs baseline: 1.0580x; 1.0580x over previous
//
#include <hip/hip_runtime.h>
#include <hip/hip_bf16.h>

// Problem constants
#define BATCH 32
#define LTOT 4096
#define CCH 64
#define NFFT 16
#define HOP 4
#define NF 9            // n_fft/2+1
#define T_FR 1025       // 1 + L/HOP
#define ICH 576         // C * NF
#define OCH 512
#define TY 1023         // conv output length
#define OUTW 128
#define KTOT 1728       // 3 taps x 576

typedef __attribute__((ext_vector_type(8))) _Float16 half8;
typedef __attribute__((ext_vector_type(4))) float floatx4;

// cos/sin(n*pi/8) for n = 0..15 — compile-time twiddles.
__device__ constexpr float C16[16] = {
    1.0f,  0.923879533f,  0.707106781f,  0.382683432f,  0.0f, -0.382683432f,
   -0.707106781f, -0.923879533f, -1.0f, -0.923879533f, -0.707106781f,
   -0.382683432f,  0.0f,  0.382683432f,  0.707106781f,  0.923879533f};
__device__ constexpr float S16[16] = {
    0.0f,  0.382683432f,  0.707106781f,  0.923879533f,  1.0f,  0.923879533f,
    0.707106781f,  0.382683432f,  0.0f, -0.382683432f, -0.707106781f,
   -0.923879533f, -1.0f, -0.923879533f, -0.707106781f, -0.382683432f};

__device__ __forceinline__ void async_copy16(const _Float16* g, _Float16* l) {
  __builtin_amdgcn_global_load_lds(
      (const __attribute__((address_space(1))) unsigned int*)g,
      (__attribute__((address_space(3))) unsigned int*)l, 16, 0, 0);
}

// R24: raw v_sqrt_f32 (~1 ulp).  Without -ffast-math, sqrtf() emits a ~25-op
// guarded sequence; x9 per row-lane it dominated the DFT VALU bill (R23 PMC:
// 850 issued ops/row-lane vs ~400 hand-counted).  The fp16 rounding right
// after makes the precision difference invisible.
__device__ __forceinline__ float fsqrt_fast(float v) {
  float r;
  asm("v_sqrt_f32 %0, %1" : "=v"(r) : "v"(v));
  return r;
}

// ---------------------------------------------------------------------------
// Kernel 1 (R23/R24): STFT magnitude + bin-pool FUSED (+ weight repack).
// One block per (w-bin, b): computes m rows s..e+1 from x directly (fp16
// round per magnitude = m_ws-materialized numerics), accumulates per-tap
// bin sums in registers, reduces across waves via LDS, writes pm[b][w][1728].
// R24 deltas vs R23 (which ran 59 us, VALUBusy 58%, Occ 46%):
//   - fsqrt_fast (above): ~-250 VALU ops of ~850 per row-lane.
//   - red shrunk [4][27][64] -> [2][27][64] via two-stage cross-wave add:
//     arena = max(xs 14.3KB, red 13.8KB) = 14.3KB -> 8 blocks/CU (was 5 at
//     27.6KB) -> 100% thread occupancy for dep-chain latency hiding.
// block 256 = 64 c x 4 tq; grid (128 w, 32 b).
// ---------------------------------------------------------------------------
__global__ __launch_bounds__(256) void stft_pool_kernel(
    const float* __restrict__ x, const float* __restrict__ weight,
    _Float16* __restrict__ pm, _Float16* __restrict__ wkr) {
  const int w = blockIdx.x, b = blockIdx.y;
  const int tid = threadIdx.x;

  // ---- weight repack slice (independent; first 1152 blocks cover it) ----
  const int gid = (b * 128 + w) * 256 + tid;
  if (gid < OCH * ICH) {
    int o = gid / ICH, i = gid - o * ICH;
    int c = i / 9, f = i - c * 9;
    const float* src = weight + (size_t)o * (ICH * 3) + i * 3;
    _Float16* dst = wkr + (size_t)o * KTOT + f * 64 + c;
#pragma unroll
    for (int k = 0; k < 3; ++k)
      dst[k * ICH] = (_Float16)src[k];
  }

  // ---- bin geometry ----
  const int s = (w * TY) >> 7;                 // first conv-output row of bin
  const int e = ((w + 1) * TY + 127) >> 7;     // one past last
  const int cnt = e - s;                       // 8 or 9
  const int R = cnt + 2;                       // m rows s..e+1 (taps 0..2)
  const float inv = 1.0f / (float)cnt;

  __shared__ float arena[56 * 64];             // 14.3 KB union: xs | red
  float* xs = arena;                           // [R*4+12 <= 56][64]
  float* red = arena;                          // [2][27][64] after barrier

  // ---- stage x rows l_base .. l_base+nrow-1 (reflect-padded), float4 ----
  const int l_base = s * 4 - 8;
  const int nrow = R * 4 + 12;                 // <= 56
  const float* xb = x + (size_t)b * LTOT * CCH;
#pragma unroll
  for (int it = 0; it < 4; ++it) {
    int u = it * 256 + tid;
    int r = u >> 4, c4 = u & 15;
    if (r < nrow) {
      int l = l_base + r;
      if (l < 0) l = -l;
      if (l >= LTOT) l = 2 * LTOT - 2 - l;
      *(floatx4*)(&xs[r * 64 + c4 * 4]) =
          *(const floatx4*)(&xb[(size_t)l * CCH + c4 * 4]);
    }
  }
  __syncthreads();

  const int c = tid & 63, tq = tid >> 6;       // wave == tq

  float acc[3][NF];
#pragma unroll
  for (int k = 0; k < 3; ++k)
#pragma unroll
    for (int f = 0; f < NF; ++f) acc[k][f] = 0.0f;

  // ---- rows tq, tq+4, tq+8 ----
#pragma unroll
  for (int it = 0; it < 3; ++it) {
    const int rl = tq + it * 4;                // local m-row index
    if (rl < R) {
      float wx[16];
#pragma unroll
      for (int j = 0; j < 16; ++j)
        wx[j] = xs[(rl * 4 + j) * 64 + c] * (0.5f * (1.0f - C16[j]));
      float sj[8], dj[8];
#pragma unroll
      for (int j = 1; j < 8; ++j) {
        sj[j] = wx[j] + wx[16 - j];
        dj[j] = wx[j] - wx[16 - j];
      }
#pragma unroll
      for (int f = 0; f < NF; ++f) {
        float re = wx[0] + ((f & 1) ? -wx[8] : wx[8]);
        float im = 0.0f;
#pragma unroll
        for (int j = 1; j < 8; ++j) {
          re += sj[j] * C16[(f * j) & 15];
          im += dj[j] * S16[(f * j) & 15];
        }
        // round through fp16 first (matches the m_ws-materialized numerics)
        const float mag = (float)(_Float16)fsqrt_fast(re * re + im * im);
        // row rl contributes to tap k iff rl-k in [0, cnt)
#pragma unroll
        for (int k = 0; k < 3; ++k)
          if ((unsigned)(rl - k) < (unsigned)cnt) acc[k][f] += mag;
      }
    }
  }

  __syncthreads();   // xs dead; arena becomes red[2][27][64]

  // ---- two-stage cross-wave reduction ----
  // stage 1: waves 0,1 write their partials
  if (tq < 2) {
#pragma unroll
    for (int k = 0; k < 3; ++k)
#pragma unroll
      for (int f = 0; f < NF; ++f)
        red[((tq * 27) + k * 9 + f) * 64 + c] = acc[k][f];
  }
  __syncthreads();
  // stage 2: waves 2,3 add into slot tq-2
  if (tq >= 2) {
#pragma unroll
    for (int k = 0; k < 3; ++k)
#pragma unroll
      for (int f = 0; f < NF; ++f) {
        const int idx = (((tq - 2) * 27) + k * 9 + f) * 64 + c;
        red[idx] += acc[k][f];
      }
  }
  __syncthreads();

  // ---- reduce 2 slots, mean, fp16, store pm[b][w][kappa] ----
  _Float16* pmo = pm + ((size_t)b * OUTW + w) * KTOT;
  for (int j = tid; j < KTOT; j += 256) {
    const int k = j / ICH;
    const int rem = j - k * ICH;
    const int f = rem >> 6;                    // kappa = k*576 + f*64 + c
    const int cc = rem & 63;
    const int base = (k * 9 + f) * 64 + cc;
    const float sum = red[base] + red[27 * 64 + base];
    pmo[j] = (_Float16)(sum * inv);
  }
}

// ---------------------------------------------------------------------------
// Kernel 2 (R22, unchanged): the collapsed GEMM.
//   out[b][w][o] = bias[o] + sum_{kappa<1728} wkr[o][kappa]*pmean[b][w][kappa]
// Tile 64(o) x 128(w = one batch), grid 256 = 1 block/CU; proven R13
// fragment/staging swizzle (conflict-free 16-row fragments).
// XCD map: all 8 o-tiles of batch b on one XCD; b = bq*8 + xcd.
// ---------------------------------------------------------------------------
__global__ __launch_bounds__(256, 2) void gemm_pooled_kernel(
    const _Float16* __restrict__ pm, const _Float16* __restrict__ wkr,
    const float* __restrict__ bias, float* __restrict__ out) {
  const int lid = blockIdx.x;            // 0..255
  const int xcd = lid & 7;
  const int rest = lid >> 3;             // 0..31
  const int m8 = rest & 7;               // o-tile 0..7
  const int bq = rest >> 3;              // 0..3
  const int b = bq * 8 + xcd;
  const int o0 = m8 * 64;

  const int tid = threadIdx.x;
  const int wave = tid >> 6, lane = tid & 63;
  const int wm = wave >> 1, wn = wave & 1;   // 2(o) x 2(w) wave grid

  __shared__ _Float16 as[64 * 64];       // 8 KB  (W rows o0..o0+63)
  __shared__ _Float16 bs[128 * 64];      // 16 KB (pmean rows, all w of b)

  floatx4 acc[2][4];
#pragma unroll
  for (int mt = 0; mt < 2; ++mt)
#pragma unroll
    for (int nt = 0; nt < 4; ++nt)
      acc[mt][nt] = (floatx4)0.0f;

  const int frow = lane & 15;
  const int quad = lane >> 4;
  const int l7 = lane & 7;
  const int srow = lane >> 3;
  const int ssrc_off = srow * KTOT + (l7 ^ srow) * 8;

  const _Float16* ab = wkr + (size_t)o0 * KTOT;
  const _Float16* bb = pm + (size_t)b * OUTW * KTOT;

  for (int kb = 0; kb < 27; ++kb) {
    const int i0 = kb * 64;
    // stage A: 8 segs of 8 rows (2 per wave)
#pragma unroll
    for (int it = 0; it < 2; ++it) {
      const int seg = wave * 2 + it;
      async_copy16(ab + (size_t)(seg * 8) * KTOT + i0 + ssrc_off,
                   &as[seg * 512]);
    }
    // stage B: 16 segs of 8 rows (4 per wave)
#pragma unroll
    for (int it = 0; it < 4; ++it) {
      const int seg = wave * 4 + it;
      async_copy16(bb + (size_t)(seg * 8) * KTOT + i0 + ssrc_off,
                   &bs[seg * 512]);
    }
    __syncthreads();   // drains vmcnt + barrier

#pragma unroll
    for (int kk2 = 0; kk2 < 2; ++kk2) {
      const int jj = kk2 * 4 + quad;
      const int coff = ((jj ^ l7) << 3);
      half8 af[2], bf[4];
#pragma unroll
      for (int mt = 0; mt < 2; ++mt)
        af[mt] = *(const half8*)(&as[(wm * 32 + mt * 16 + frow) * 64 + coff]);
#pragma unroll
      for (int nt = 0; nt < 4; ++nt)
        bf[nt] = *(const half8*)(&bs[(wn * 64 + nt * 16 + frow) * 64 + coff]);
      // first operand = w-fragment => D row (quad*4+reg) = w, D col = o
#pragma unroll
      for (int mt = 0; mt < 2; ++mt)
#pragma unroll
        for (int nt = 0; nt < 4; ++nt)
          acc[mt][nt] = __builtin_amdgcn_mfma_f32_16x16x32_f16(
              bf[nt], af[mt], acc[mt][nt], 0, 0, 0);
    }
    __syncthreads();
  }

  // epilogue: out[b][w][o] fp32 = bias + acc.  mt inner => 128 B contiguous
  // per (nt,r) per wave (L2 write-combine pattern).
  const int col = lane & 15;
  float* ob = out + (size_t)b * OUTW * OCH;
#pragma unroll
  for (int nt = 0; nt < 4; ++nt) {
    const int wb = wn * 64 + nt * 16 + quad * 4;
#pragma unroll
    for (int r = 0; r < 4; ++r) {
      const int w = wb + r;
#pragma unroll
      for (int mt = 0; mt < 2; ++mt) {
        const int o = o0 + wm * 32 + mt * 16 + col;
        ob[(size_t)w * OCH + o] = bias[o] + acc[mt][nt][r];
      }
    }
  }
}

// ---------------------------------------------------------------------------
extern "C" void kernel_launch(void* const* d_in, const int* in_sizes, int n_in,
                              void* d_out, int out_size, void* d_ws, size_t ws_size,
                              hipStream_t stream) {
  const float* x = (const float*)d_in[0];       // [32, 4096, 64]
  const float* weight = (const float*)d_in[1];  // [512, 576, 3]
  const float* bias = (const float*)d_in[2];    // [512]
  float* out = (float*)d_out;                   // [32, 128, 512]

  char* ws = (char*)d_ws;
  const size_t w_bytes = (size_t)OCH * KTOT * sizeof(_Float16);  // 1,769,472
  _Float16* wkr = (_Float16*)ws;
  _Float16* pm = (_Float16*)(ws + w_bytes);   // [32][128][1728] fp16, 14.2 MB

  hipLaunchKernelGGL(stft_pool_kernel, dim3(OUTW, BATCH), dim3(256), 0,
                     stream, x, weight, pm, wkr);
  hipLaunchKernelGGL(gemm_pooled_kernel, dim3(256), dim3(256), 0, stream,
                     pm, wkr, bias, out);
}

// Round 12
// 114.389 us; speedup vs baseline: 1.1550x; 1.0917x over previous
//
#include <hip/hip_runtime.h>
#include <hip/hip_bf16.h>

// Problem constants
#define BATCH 32
#define LTOT 4096
#define CCH 64
#define NFFT 16
#define HOP 4
#define NF 9            // n_fft/2+1
#define T_FR 1025       // 1 + L/HOP
#define ICH 576         // C * NF
#define OCH 512
#define TY 1023         // conv output length
#define OUTW 128
#define KTOT 1728       // 3 taps x 576

typedef __attribute__((ext_vector_type(8))) _Float16 half8;
typedef __attribute__((ext_vector_type(4))) float floatx4;

// cos(n*pi/8) for n = 0..15 — used only for the window now.
__device__ constexpr float C16[16] = {
    1.0f,  0.923879533f,  0.707106781f,  0.382683432f,  0.0f, -0.382683432f,
   -0.707106781f, -0.923879533f, -1.0f, -0.923879533f, -0.707106781f,
   -0.382683432f,  0.0f,  0.382683432f,  0.707106781f,  0.923879533f};

#define C1F 0.923879533f   // cos(pi/8)
#define C2F 0.707106781f   // cos(2pi/8)
#define C3F 0.382683432f   // cos(3pi/8) = sin(pi/8)

__device__ __forceinline__ void async_copy16(const _Float16* g, _Float16* l) {
  __builtin_amdgcn_global_load_lds(
      (const __attribute__((address_space(1))) unsigned int*)g,
      (__attribute__((address_space(3))) unsigned int*)l, 16, 0, 0);
}

// R24: raw v_sqrt_f32 (~1 ulp; fp16 rounding right after makes it exact
// enough).  sqrtf() without -ffast-math is a ~25-op guarded sequence.
__device__ __forceinline__ float fsqrt_fast(float v) {
  float r;
  asm("v_sqrt_f32 %0, %1" : "=v"(r) : "v"(v));
  return r;
}

// ---------------------------------------------------------------------------
// Kernel 1 (R23-R26): STFT magnitude + bin-pool FUSED (+ weight repack).
// One block per (w-bin, b): computes m rows s..e+1 from x directly (fp16
// round per magnitude = m_ws-materialized numerics), accumulates per-tap
// bin sums in registers, reduces across waves via LDS, writes pm[b][w][1728].
// R25/R26: factored 16-pt real DFT (~135 -> ~60 core VALU ops; kernel is
// VALU-issue-bound per R23 PMC: MfmaUtil 0 / VALUBusy 58% / HBM 10%).
// R26 BUGFIX of R25 (absmax 0.58): f=8 fold is EVEN — cos(8j pi/8)=(-1)^j,
// j=8 term = +wx[8] -> re8 = wxp + (Se - So).  R25 wrote wxm (error 2*wx[8]).
// Identity ledger (re-verified term-by-term, R25 post-mortem):
//   re1 = wxm + C2*u1 + (C1*u2 + C3*u3) = A1+B1   re7 = A1-B1   [ok]
//   im1 = d4 + C2*v1 + (C3*v2 + C1*v3) = P1+Q1    im7 = Q1-P1   [ok]
//   re3 = wxm - C2*u1 + (C3*u2 - C1*u3) = A3+B3   re5 = A3-B3   [ok]
//   im3 = C2*v1 - d4 + (C1*v2 - C3*v3) = P3+Q3    im5 = Q3-P3   [ok]
//   re2 = wxp - s4 + C2*(s1-s3-s5+s7) = A2+B2     re6 = A2-B2   [ok]
//   im2 = (d2-d6) + C2*(d1+d3-d5-d7) = P2+Q2      im6 = Q2-P2   [ok]
//   re4 = wxp-s2+s4-s6   im4 = d1-d3+d5-d7                      [ok]
//   re0 = wxp+Se+So      re8 = wxp+Se-So (FIXED)   im0=im8=0    [ok]
// block 256 = 64 c x 4 tq; grid (128 w, 32 b); arena 14.3 KB -> 8 blocks/CU.
// ---------------------------------------------------------------------------
__global__ __launch_bounds__(256) void stft_pool_kernel(
    const float* __restrict__ x, const float* __restrict__ weight,
    _Float16* __restrict__ pm, _Float16* __restrict__ wkr) {
  const int w = blockIdx.x, b = blockIdx.y;
  const int tid = threadIdx.x;

  // ---- weight repack slice (independent; first 1152 blocks cover it) ----
  const int gid = (b * 128 + w) * 256 + tid;
  if (gid < OCH * ICH) {
    int o = gid / ICH, i = gid - o * ICH;
    int c = i / 9, f = i - c * 9;
    const float* src = weight + (size_t)o * (ICH * 3) + i * 3;
    _Float16* dst = wkr + (size_t)o * KTOT + f * 64 + c;
#pragma unroll
    for (int k = 0; k < 3; ++k)
      dst[k * ICH] = (_Float16)src[k];
  }

  // ---- bin geometry ----
  const int s = (w * TY) >> 7;                 // first conv-output row of bin
  const int e = ((w + 1) * TY + 127) >> 7;     // one past last
  const int cnt = e - s;                       // 8 or 9
  const int R = cnt + 2;                       // m rows s..e+1 (taps 0..2)
  const float inv = 1.0f / (float)cnt;

  __shared__ float arena[56 * 64];             // 14.3 KB union: xs | red
  float* xs = arena;                           // [R*4+12 <= 56][64]
  float* red = arena;                          // [2][27][64] after barrier

  // ---- stage x rows l_base .. l_base+nrow-1 (reflect-padded), float4 ----
  const int l_base = s * 4 - 8;
  const int nrow = R * 4 + 12;                 // <= 56
  const float* xb = x + (size_t)b * LTOT * CCH;
#pragma unroll
  for (int it = 0; it < 4; ++it) {
    int u = it * 256 + tid;
    int r = u >> 4, c4 = u & 15;
    if (r < nrow) {
      int l = l_base + r;
      if (l < 0) l = -l;
      if (l >= LTOT) l = 2 * LTOT - 2 - l;
      *(floatx4*)(&xs[r * 64 + c4 * 4]) =
          *(const floatx4*)(&xb[(size_t)l * CCH + c4 * 4]);
    }
  }
  __syncthreads();

  const int c = tid & 63, tq = tid >> 6;       // wave == tq

  float acc[3][NF];
#pragma unroll
  for (int k = 0; k < 3; ++k)
#pragma unroll
    for (int f = 0; f < NF; ++f) acc[k][f] = 0.0f;

  // ---- rows tq, tq+4, tq+8 ----
#pragma unroll
  for (int it = 0; it < 3; ++it) {
    const int rl = tq + it * 4;                // local m-row index
    if (rl < R) {
      float wx[16];
#pragma unroll
      for (int j = 0; j < 16; ++j)
        wx[j] = xs[(rl * 4 + j) * 64 + c] * (0.5f * (1.0f - C16[j]));
      // fold j <-> 16-j
      const float s1 = wx[1] + wx[15], d1 = wx[1] - wx[15];
      const float s2 = wx[2] + wx[14], d2 = wx[2] - wx[14];
      const float s3 = wx[3] + wx[13], d3 = wx[3] - wx[13];
      const float s4 = wx[4] + wx[12], d4 = wx[4] - wx[12];
      const float s5 = wx[5] + wx[11], d5 = wx[5] - wx[11];
      const float s6 = wx[6] + wx[10], d6 = wx[6] - wx[10];
      const float s7 = wx[7] + wx[9],  d7 = wx[7] - wx[9];
      const float wxp = wx[0] + wx[8], wxm = wx[0] - wx[8];
      // shared sums
      const float u1 = s2 - s6, u2 = s1 - s7, u3 = s3 - s5;
      const float v1 = d2 + d6, v2 = d1 + d7, v3 = d3 + d5;
      const float Se = s2 + s4 + s6;
      const float So = (s1 + s3) + (s5 + s7);
      // f = 0, 8: im == 0 (even fold both use wxp)
      const float re0 = wxp + Se + So;
      const float re8 = wxp + (Se - So);
      // pair (1,7) and (3,5) share products
      const float tA = C2F * u1;
      const float A1 = wxm + tA, A3 = wxm - tA;
      const float B1 = C1F * u2 + C3F * u3;
      const float B3 = C3F * u2 - C1F * u3;
      const float tP = C2F * v1;
      const float P1 = d4 + tP, P3 = tP - d4;
      const float Q1 = C3F * v2 + C1F * v3;
      const float Q3 = C1F * v2 - C3F * v3;
      // pair (2,6)
      const float A2 = wxp - s4;
      const float B2 = C2F * (((s1 - s3) - s5) + s7);
      const float P2 = d2 - d6;
      const float Q2 = C2F * (((d1 + d3) - d5) - d7);
      // f = 4
      const float re4 = ((wxp - s2) + s4) - s6;
      const float im4 = ((d1 - d3) + d5) - d7;

      float mg[NF];
      mg[0] = (float)(_Float16)fabsf(re0);
      mg[8] = (float)(_Float16)fabsf(re8);
      {
        const float r1 = A1 + B1, i1 = P1 + Q1;
        mg[1] = (float)(_Float16)fsqrt_fast(r1 * r1 + i1 * i1);
        const float r7 = A1 - B1, i7 = Q1 - P1;
        mg[7] = (float)(_Float16)fsqrt_fast(r7 * r7 + i7 * i7);
        const float r2 = A2 + B2, i2 = P2 + Q2;
        mg[2] = (float)(_Float16)fsqrt_fast(r2 * r2 + i2 * i2);
        const float r6 = A2 - B2, i6 = Q2 - P2;
        mg[6] = (float)(_Float16)fsqrt_fast(r6 * r6 + i6 * i6);
        const float r3 = A3 + B3, i3 = P3 + Q3;
        mg[3] = (float)(_Float16)fsqrt_fast(r3 * r3 + i3 * i3);
        const float r5 = A3 - B3, i5 = Q3 - P3;
        mg[5] = (float)(_Float16)fsqrt_fast(r5 * r5 + i5 * i5);
        mg[4] = (float)(_Float16)fsqrt_fast(re4 * re4 + im4 * im4);
      }
      // row rl contributes to tap k iff rl-k in [0, cnt); rl, cnt are
      // wave-uniform -> scalar branches, only taken adds cost VALU.
#pragma unroll
      for (int k = 0; k < 3; ++k)
        if ((unsigned)(rl - k) < (unsigned)cnt)
#pragma unroll
          for (int f = 0; f < NF; ++f) acc[k][f] += mg[f];
    }
  }

  __syncthreads();   // xs dead; arena becomes red[2][27][64]

  // ---- two-stage cross-wave reduction ----
  if (tq < 2) {
#pragma unroll
    for (int k = 0; k < 3; ++k)
#pragma unroll
      for (int f = 0; f < NF; ++f)
        red[((tq * 27) + k * 9 + f) * 64 + c] = acc[k][f];
  }
  __syncthreads();
  if (tq >= 2) {
#pragma unroll
    for (int k = 0; k < 3; ++k)
#pragma unroll
      for (int f = 0; f < NF; ++f) {
        const int idx = (((tq - 2) * 27) + k * 9 + f) * 64 + c;
        red[idx] += acc[k][f];
      }
  }
  __syncthreads();

  // ---- reduce 2 slots, mean, fp16, store pm[b][w][kappa] ----
  _Float16* pmo = pm + ((size_t)b * OUTW + w) * KTOT;
  for (int j = tid; j < KTOT; j += 256) {
    const int k = j / ICH;
    const int rem = j - k * ICH;
    const int f = rem >> 6;                    // kappa = k*576 + f*64 + c
    const int cc = rem & 63;
    const int base = (k * 9 + f) * 64 + cc;
    const float sum = red[base] + red[27 * 64 + base];
    pmo[j] = (_Float16)(sum * inv);
  }
}

// ---------------------------------------------------------------------------
// Kernel 2 (R22, unchanged): the collapsed GEMM.
//   out[b][w][o] = bias[o] + sum_{kappa<1728} wkr[o][kappa]*pmean[b][w][kappa]
// Tile 64(o) x 128(w = one batch), grid 256 = 1 block/CU; proven R13
// fragment/staging swizzle (conflict-free 16-row fragments).
// XCD map: all 8 o-tiles of batch b on one XCD; b = bq*8 + xcd.
// ---------------------------------------------------------------------------
__global__ __launch_bounds__(256, 2) void gemm_pooled_kernel(
    const _Float16* __restrict__ pm, const _Float16* __restrict__ wkr,
    const float* __restrict__ bias, float* __restrict__ out) {
  const int lid = blockIdx.x;            // 0..255
  const int xcd = lid & 7;
  const int rest = lid >> 3;             // 0..31
  const int m8 = rest & 7;               // o-tile 0..7
  const int bq = rest >> 3;              // 0..3
  const int b = bq * 8 + xcd;
  const int o0 = m8 * 64;

  const int tid = threadIdx.x;
  const int wave = tid >> 6, lane = tid & 63;
  const int wm = wave >> 1, wn = wave & 1;   // 2(o) x 2(w) wave grid

  __shared__ _Float16 as[64 * 64];       // 8 KB  (W rows o0..o0+63)
  __shared__ _Float16 bs[128 * 64];      // 16 KB (pmean rows, all w of b)

  floatx4 acc[2][4];
#pragma unroll
  for (int mt = 0; mt < 2; ++mt)
#pragma unroll
    for (int nt = 0; nt < 4; ++nt)
      acc[mt][nt] = (floatx4)0.0f;

  const int frow = lane & 15;
  const int quad = lane >> 4;
  const int l7 = lane & 7;
  const int srow = lane >> 3;
  const int ssrc_off = srow * KTOT + (l7 ^ srow) * 8;

  const _Float16* ab = wkr + (size_t)o0 * KTOT;
  const _Float16* bb = pm + (size_t)b * OUTW * KTOT;

  for (int kb = 0; kb < 27; ++kb) {
    const int i0 = kb * 64;
    // stage A: 8 segs of 8 rows (2 per wave)
#pragma unroll
    for (int it = 0; it < 2; ++it) {
      const int seg = wave * 2 + it;
      async_copy16(ab + (size_t)(seg * 8) * KTOT + i0 + ssrc_off,
                   &as[seg * 512]);
    }
    // stage B: 16 segs of 8 rows (4 per wave)
#pragma unroll
    for (int it = 0; it < 4; ++it) {
      const int seg = wave * 4 + it;
      async_copy16(bb + (size_t)(seg * 8) * KTOT + i0 + ssrc_off,
                   &bs[seg * 512]);
    }
    __syncthreads();   // drains vmcnt + barrier

#pragma unroll
    for (int kk2 = 0; kk2 < 2; ++kk2) {
      const int jj = kk2 * 4 + quad;
      const int coff = ((jj ^ l7) << 3);
      half8 af[2], bf[4];
#pragma unroll
      for (int mt = 0; mt < 2; ++mt)
        af[mt] = *(const half8*)(&as[(wm * 32 + mt * 16 + frow) * 64 + coff]);
#pragma unroll
      for (int nt = 0; nt < 4; ++nt)
        bf[nt] = *(const half8*)(&bs[(wn * 64 + nt * 16 + frow) * 64 + coff]);
      // first operand = w-fragment => D row (quad*4+reg) = w, D col = o
#pragma unroll
      for (int mt = 0; mt < 2; ++mt)
#pragma unroll
        for (int nt = 0; nt < 4; ++nt)
          acc[mt][nt] = __builtin_amdgcn_mfma_f32_16x16x32_f16(
              bf[nt], af[mt], acc[mt][nt], 0, 0, 0);
    }
    __syncthreads();
  }

  // epilogue: out[b][w][o] fp32 = bias + acc.  mt inner => 128 B contiguous
  // per (nt,r) per wave (L2 write-combine pattern).
  const int col = lane & 15;
  float* ob = out + (size_t)b * OUTW * OCH;
#pragma unroll
  for (int nt = 0; nt < 4; ++nt) {
    const int wb = wn * 64 + nt * 16 + quad * 4;
#pragma unroll
    for (int r = 0; r < 4; ++r) {
      const int w = wb + r;
#pragma unroll
      for (int mt = 0; mt < 2; ++mt) {
        const int o = o0 + wm * 32 + mt * 16 + col;
        ob[(size_t)w * OCH + o] = bias[o] + acc[mt][nt][r];
      }
    }
  }
}

// ---------------------------------------------------------------------------
extern "C" void kernel_launch(void* const* d_in, const int* in_sizes, int n_in,
                              void* d_out, int out_size, void* d_ws, size_t ws_size,
                              hipStream_t stream) {
  const float* x = (const float*)d_in[0];       // [32, 4096, 64]
  const float* weight = (const float*)d_in[1];  // [512, 576, 3]
  const float* bias = (const float*)d_in[2];    // [512]
  float* out = (float*)d_out;                   // [32, 128, 512]

  char* ws = (char*)d_ws;
  const size_t w_bytes = (size_t)OCH * KTOT * sizeof(_Float16);  // 1,769,472
  _Float16* wkr = (_Float16*)ws;
  _Float16* pm = (_Float16*)(ws + w_bytes);   // [32][128][1728] fp16, 14.2 MB

  hipLaunchKernelGGL(stft_pool_kernel, dim3(OUTW, BATCH), dim3(256), 0,
                     stream, x, weight, pm, wkr);
  hipLaunchKernelGGL(gemm_pooled_kernel, dim3(256), dim3(256), 0, stream,
                     pm, wkr, bias, out);
}

// Round 13
// 112.454 us; speedup vs baseline: 1.1749x; 1.0172x over previous
//
#include <hip/hip_runtime.h>
#include <hip/hip_bf16.h>

// Problem constants
#define BATCH 32
#define LTOT 4096
#define CCH 64
#define NFFT 16
#define HOP 4
#define NF 9            // n_fft/2+1
#define T_FR 1025       // 1 + L/HOP
#define ICH 576         // C * NF
#define OCH 512
#define TY 1023         // conv output length
#define OUTW 128
#define KTOT 1728       // 3 taps x 576

typedef __attribute__((ext_vector_type(8))) _Float16 half8;
typedef __attribute__((ext_vector_type(4))) float floatx4;

// cos(n*pi/8) for n = 0..15 — used only for the window now.
__device__ constexpr float C16[16] = {
    1.0f,  0.923879533f,  0.707106781f,  0.382683432f,  0.0f, -0.382683432f,
   -0.707106781f, -0.923879533f, -1.0f, -0.923879533f, -0.707106781f,
   -0.382683432f,  0.0f,  0.382683432f,  0.707106781f,  0.923879533f};

#define C1F 0.923879533f   // cos(pi/8)
#define C2F 0.707106781f   // cos(2pi/8)
#define C3F 0.382683432f   // cos(3pi/8) = sin(pi/8)

__device__ __forceinline__ void async_copy16(const _Float16* g, _Float16* l) {
  __builtin_amdgcn_global_load_lds(
      (const __attribute__((address_space(1))) unsigned int*)g,
      (__attribute__((address_space(3))) unsigned int*)l, 16, 0, 0);
}

// R24: raw v_sqrt_f32 (~1 ulp).  sqrtf() without -ffast-math is a ~25-op
// guarded sequence.
__device__ __forceinline__ float fsqrt_fast(float v) {
  float r;
  asm("v_sqrt_f32 %0, %1" : "=v"(r) : "v"(v));
  return r;
}

// raw barrier + counted vmcnt (no compiler-inserted vmcnt(0) drain).
// Proven correct in the R17 conv experiment (no perf gain THERE because that
// kernel was pipe-sum-bound; gemm_pooled is stage-latency-bound — T3/T4's
// actual regime).
#define SBAR() asm volatile("s_barrier" ::: "memory")
#define WAITV(N) asm volatile("s_waitcnt vmcnt(" #N ")" ::: "memory")

// ---------------------------------------------------------------------------
// Kernel 1 (R23-R27): STFT magnitude + bin-pool FUSED (+ weight repack).
// One block per (w-bin, b): computes m rows s..e+1 from x directly,
// accumulates per-tap bin sums in registers, reduces across waves via LDS,
// writes pm[b][w][1728] fp16.
// R25/R26: factored 16-pt real DFT (identity ledger in R26 notes; f=8 fold
// is EVEN: re8 = wxp + (Se - So)).
// R27: dropped the per-magnitude (float)(_Float16) round-trip (-18 v_cvt
// per row-lane).  It existed only to mimic the deleted m_ws materialization;
// removing it moves numerics TOWARD the fp32 reference (one less
// quantization stage).  pm itself is still fp16 (GEMM input).
// block 256 = 64 c x 4 tq; grid (128 w, 32 b); arena 14.3 KB -> 8 blocks/CU.
// ---------------------------------------------------------------------------
__global__ __launch_bounds__(256) void stft_pool_kernel(
    const float* __restrict__ x, const float* __restrict__ weight,
    _Float16* __restrict__ pm, _Float16* __restrict__ wkr) {
  const int w = blockIdx.x, b = blockIdx.y;
  const int tid = threadIdx.x;

  // ---- weight repack slice (independent; first 1152 blocks cover it) ----
  const int gid = (b * 128 + w) * 256 + tid;
  if (gid < OCH * ICH) {
    int o = gid / ICH, i = gid - o * ICH;
    int c = i / 9, f = i - c * 9;
    const float* src = weight + (size_t)o * (ICH * 3) + i * 3;
    _Float16* dst = wkr + (size_t)o * KTOT + f * 64 + c;
#pragma unroll
    for (int k = 0; k < 3; ++k)
      dst[k * ICH] = (_Float16)src[k];
  }

  // ---- bin geometry ----
  const int s = (w * TY) >> 7;                 // first conv-output row of bin
  const int e = ((w + 1) * TY + 127) >> 7;     // one past last
  const int cnt = e - s;                       // 8 or 9
  const int R = cnt + 2;                       // m rows s..e+1 (taps 0..2)
  const float inv = 1.0f / (float)cnt;

  __shared__ float arena[56 * 64];             // 14.3 KB union: xs | red
  float* xs = arena;                           // [R*4+12 <= 56][64]
  float* red = arena;                          // [2][27][64] after barrier

  // ---- stage x rows l_base .. l_base+nrow-1 (reflect-padded), float4 ----
  const int l_base = s * 4 - 8;
  const int nrow = R * 4 + 12;                 // <= 56
  const float* xb = x + (size_t)b * LTOT * CCH;
#pragma unroll
  for (int it = 0; it < 4; ++it) {
    int u = it * 256 + tid;
    int r = u >> 4, c4 = u & 15;
    if (r < nrow) {
      int l = l_base + r;
      if (l < 0) l = -l;
      if (l >= LTOT) l = 2 * LTOT - 2 - l;
      *(floatx4*)(&xs[r * 64 + c4 * 4]) =
          *(const floatx4*)(&xb[(size_t)l * CCH + c4 * 4]);
    }
  }
  __syncthreads();

  const int c = tid & 63, tq = tid >> 6;       // wave == tq

  float acc[3][NF];
#pragma unroll
  for (int k = 0; k < 3; ++k)
#pragma unroll
    for (int f = 0; f < NF; ++f) acc[k][f] = 0.0f;

  // ---- rows tq, tq+4, tq+8 ----
#pragma unroll
  for (int it = 0; it < 3; ++it) {
    const int rl = tq + it * 4;                // local m-row index
    if (rl < R) {
      float wx[16];
#pragma unroll
      for (int j = 0; j < 16; ++j)
        wx[j] = xs[(rl * 4 + j) * 64 + c] * (0.5f * (1.0f - C16[j]));
      // fold j <-> 16-j
      const float s1 = wx[1] + wx[15], d1 = wx[1] - wx[15];
      const float s2 = wx[2] + wx[14], d2 = wx[2] - wx[14];
      const float s3 = wx[3] + wx[13], d3 = wx[3] - wx[13];
      const float s4 = wx[4] + wx[12], d4 = wx[4] - wx[12];
      const float s5 = wx[5] + wx[11], d5 = wx[5] - wx[11];
      const float s6 = wx[6] + wx[10], d6 = wx[6] - wx[10];
      const float s7 = wx[7] + wx[9],  d7 = wx[7] - wx[9];
      const float wxp = wx[0] + wx[8], wxm = wx[0] - wx[8];
      // shared sums
      const float u1 = s2 - s6, u2 = s1 - s7, u3 = s3 - s5;
      const float v1 = d2 + d6, v2 = d1 + d7, v3 = d3 + d5;
      const float Se = s2 + s4 + s6;
      const float So = (s1 + s3) + (s5 + s7);
      // f = 0, 8: im == 0 (even fold both use wxp)
      const float re0 = wxp + Se + So;
      const float re8 = wxp + (Se - So);
      // pair (1,7) and (3,5) share products
      const float tA = C2F * u1;
      const float A1 = wxm + tA, A3 = wxm - tA;
      const float B1 = C1F * u2 + C3F * u3;
      const float B3 = C3F * u2 - C1F * u3;
      const float tP = C2F * v1;
      const float P1 = d4 + tP, P3 = tP - d4;
      const float Q1 = C3F * v2 + C1F * v3;
      const float Q3 = C1F * v2 - C3F * v3;
      // pair (2,6)
      const float A2 = wxp - s4;
      const float B2 = C2F * (((s1 - s3) - s5) + s7);
      const float P2 = d2 - d6;
      const float Q2 = C2F * (((d1 + d3) - d5) - d7);
      // f = 4
      const float re4 = ((wxp - s2) + s4) - s6;
      const float im4 = ((d1 - d3) + d5) - d7;

      float mg[NF];
      mg[0] = fabsf(re0);
      mg[8] = fabsf(re8);
      {
        const float r1 = A1 + B1, i1 = P1 + Q1;
        mg[1] = fsqrt_fast(r1 * r1 + i1 * i1);
        const float r7 = A1 - B1, i7 = Q1 - P1;
        mg[7] = fsqrt_fast(r7 * r7 + i7 * i7);
        const float r2 = A2 + B2, i2 = P2 + Q2;
        mg[2] = fsqrt_fast(r2 * r2 + i2 * i2);
        const float r6 = A2 - B2, i6 = Q2 - P2;
        mg[6] = fsqrt_fast(r6 * r6 + i6 * i6);
        const float r3 = A3 + B3, i3 = P3 + Q3;
        mg[3] = fsqrt_fast(r3 * r3 + i3 * i3);
        const float r5 = A3 - B3, i5 = Q3 - P3;
        mg[5] = fsqrt_fast(r5 * r5 + i5 * i5);
        mg[4] = fsqrt_fast(re4 * re4 + im4 * im4);
      }
      // row rl contributes to tap k iff rl-k in [0, cnt); rl, cnt are
      // wave-uniform -> scalar branches, only taken adds cost VALU.
#pragma unroll
      for (int k = 0; k < 3; ++k)
        if ((unsigned)(rl - k) < (unsigned)cnt)
#pragma unroll
          for (int f = 0; f < NF; ++f) acc[k][f] += mg[f];
    }
  }

  __syncthreads();   // xs dead; arena becomes red[2][27][64]

  // ---- two-stage cross-wave reduction ----
  if (tq < 2) {
#pragma unroll
    for (int k = 0; k < 3; ++k)
#pragma unroll
      for (int f = 0; f < NF; ++f)
        red[((tq * 27) + k * 9 + f) * 64 + c] = acc[k][f];
  }
  __syncthreads();
  if (tq >= 2) {
#pragma unroll
    for (int k = 0; k < 3; ++k)
#pragma unroll
      for (int f = 0; f < NF; ++f) {
        const int idx = (((tq - 2) * 27) + k * 9 + f) * 64 + c;
        red[idx] += acc[k][f];
      }
  }
  __syncthreads();

  // ---- reduce 2 slots, mean, fp16, store pm[b][w][kappa] ----
  _Float16* pmo = pm + ((size_t)b * OUTW + w) * KTOT;
  for (int j = tid; j < KTOT; j += 256) {
    const int k = j / ICH;
    const int rem = j - k * ICH;
    const int f = rem >> 6;                    // kappa = k*576 + f*64 + c
    const int cc = rem & 63;
    const int base = (k * 9 + f) * 64 + cc;
    const float sum = red[base] + red[27 * 64 + base];
    pmo[j] = (_Float16)(sum * inv);
  }
}

// ---------------------------------------------------------------------------
// Kernel 2 (R22/R27): the collapsed GEMM, now double-buffered.
//   out[b][w][o] = bias[o] + sum_{kappa<1728} wkr[o][kappa]*pmean[b][w][kappa]
// R27: the R22 version staged each k-step and immediately drained vmcnt(0)
// at __syncthreads — a naked ~900-cyc HBM/L2 latency per step, 1 block/CU,
// no TLP to hide it: 27 x (900 + 310 MFMA) ~ 16 us (matches ledger).
// Now: as/bs double-buffered (48 KB), step k+1's 6 copies/wave issued
// BEFORE computing step k, raw s_barrier + counted vmcnt(6) (per-wave
// counts uniform: 2 A + 4 B; FIFO -> wait 6 = all of step k's complete).
// Tile 64(o) x 128(w = one batch), grid 256 = 1 block/CU; proven R13
// fragment/staging swizzle (conflict-free 16-row fragments).
// XCD map: all 8 o-tiles of batch b on one XCD; b = bq*8 + xcd.
// ---------------------------------------------------------------------------
__global__ __launch_bounds__(256, 2) void gemm_pooled_kernel(
    const _Float16* __restrict__ pm, const _Float16* __restrict__ wkr,
    const float* __restrict__ bias, float* __restrict__ out) {
  const int lid = blockIdx.x;            // 0..255
  const int xcd = lid & 7;
  const int rest = lid >> 3;             // 0..31
  const int m8 = rest & 7;               // o-tile 0..7
  const int bq = rest >> 3;              // 0..3
  const int b = bq * 8 + xcd;
  const int o0 = m8 * 64;

  const int tid = threadIdx.x;
  const int wave = tid >> 6, lane = tid & 63;
  const int wm = wave >> 1, wn = wave & 1;   // 2(o) x 2(w) wave grid

  __shared__ _Float16 as[2][64 * 64];    // 2 x 8 KB  (W rows o0..o0+63)
  __shared__ _Float16 bs[2][128 * 64];   // 2 x 16 KB (pmean rows, all w of b)

  floatx4 acc[2][4];
#pragma unroll
  for (int mt = 0; mt < 2; ++mt)
#pragma unroll
    for (int nt = 0; nt < 4; ++nt)
      acc[mt][nt] = (floatx4)0.0f;

  const int frow = lane & 15;
  const int quad = lane >> 4;
  const int l7 = lane & 7;
  const int srow = lane >> 3;
  const int ssrc_off = srow * KTOT + (l7 ^ srow) * 8;

  const _Float16* ab = wkr + (size_t)o0 * KTOT;
  const _Float16* bb = pm + (size_t)b * OUTW * KTOT;

  // per-wave per-step vmem: 2 A copies then 4 B copies (FIFO, uniform)
#define GSTAGE(kbx, buf)                                                     \
  {                                                                          \
    const int i0s = (kbx) * 64;                                              \
    _Pragma("unroll") for (int it = 0; it < 2; ++it) {                       \
      const int seg = wave * 2 + it;                                         \
      async_copy16(ab + (size_t)(seg * 8) * KTOT + i0s + ssrc_off,           \
                   &as[buf][seg * 512]);                                     \
    }                                                                        \
    _Pragma("unroll") for (int it = 0; it < 4; ++it) {                       \
      const int seg = wave * 4 + it;                                         \
      async_copy16(bb + (size_t)(seg * 8) * KTOT + i0s + ssrc_off,           \
                   &bs[buf][seg * 512]);                                     \
    }                                                                        \
  }

  GSTAGE(0, 0);
  for (int kb = 0; kb < 27; ++kb) {
    const int cur = kb & 1;
    if (kb < 26) {
      GSTAGE(kb + 1, cur ^ 1);
      WAITV(6);          // step kb's 6 copies complete; kb+1's stay in flight
    } else {
      WAITV(0);
    }
    SBAR();              // all waves: as[cur]/bs[cur] valid

#pragma unroll
    for (int kk2 = 0; kk2 < 2; ++kk2) {
      const int jj = kk2 * 4 + quad;
      const int coff = ((jj ^ l7) << 3);
      half8 af[2], bf[4];
#pragma unroll
      for (int mt = 0; mt < 2; ++mt)
        af[mt] =
            *(const half8*)(&as[cur][(wm * 32 + mt * 16 + frow) * 64 + coff]);
#pragma unroll
      for (int nt = 0; nt < 4; ++nt)
        bf[nt] =
            *(const half8*)(&bs[cur][(wn * 64 + nt * 16 + frow) * 64 + coff]);
      // first operand = w-fragment => D row (quad*4+reg) = w, D col = o
#pragma unroll
      for (int mt = 0; mt < 2; ++mt)
#pragma unroll
        for (int nt = 0; nt < 4; ++nt)
          acc[mt][nt] = __builtin_amdgcn_mfma_f32_16x16x32_f16(
              bf[nt], af[mt], acc[mt][nt], 0, 0, 0);
    }
    SBAR();              // reads of buf cur done before kb+2's DMA reuses it
  }

  // epilogue: out[b][w][o] fp32 = bias + acc.  mt inner => 128 B contiguous
  // per (nt,r) per wave (L2 write-combine pattern).
  const int col = lane & 15;
  float* ob = out + (size_t)b * OUTW * OCH;
#pragma unroll
  for (int nt = 0; nt < 4; ++nt) {
    const int wb = wn * 64 + nt * 16 + quad * 4;
#pragma unroll
    for (int r = 0; r < 4; ++r) {
      const int w = wb + r;
#pragma unroll
      for (int mt = 0; mt < 2; ++mt) {
        const int o = o0 + wm * 32 + mt * 16 + col;
        ob[(size_t)w * OCH + o] = bias[o] + acc[mt][nt][r];
      }
    }
  }
}

// ---------------------------------------------------------------------------
extern "C" void kernel_launch(void* const* d_in, const int* in_sizes, int n_in,
                              void* d_out, int out_size, void* d_ws, size_t ws_size,
                              hipStream_t stream) {
  const float* x = (const float*)d_in[0];       // [32, 4096, 64]
  const float* weight = (const float*)d_in[1];  // [512, 576, 3]
  const float* bias = (const float*)d_in[2];    // [512]
  float* out = (float*)d_out;                   // [32, 128, 512]

  char* ws = (char*)d_ws;
  const size_t w_bytes = (size_t)OCH * KTOT * sizeof(_Float16);  // 1,769,472
  _Float16* wkr = (_Float16*)ws;
  _Float16* pm = (_Float16*)(ws + w_bytes);   // [32][128][1728] fp16, 14.2 MB

  hipLaunchKernelGGL(stft_pool_kernel, dim3(OUTW, BATCH), dim3(256), 0,
                     stream, x, weight, pm, wkr);
  hipLaunchKernelGGL(gemm_pooled_kernel, dim3(256), dim3(256), 0, stream,
                     pm, wkr, bias, out);
}